// Round 12
// baseline (372.255 us; speedup 1.0000x reference)
//
#include <hip/hip_runtime.h>
#include <hip/hip_bf16.h>

#define NTOK 2048
#define EMBED 512
#define NHEADS 8
#define HD 64
#define NBINS 512
#define MAXSEL 256

typedef unsigned short u16;
typedef unsigned int u32;

__device__ __forceinline__ float lof(u32 u){ return __uint_as_float(u << 16); }
__device__ __forceinline__ float hif(u32 u){ return __uint_as_float(u & 0xffff0000u); }
__device__ __forceinline__ float bf2f(u16 u){ return __uint_as_float(((u32)u) << 16); }
__device__ __forceinline__ u16 f2b(float f){
    __hip_bfloat16 h = __float2bfloat16(f);
    return *(u16*)&h;
}
__device__ __forceinline__ u32 pack2(float lo, float hi){
    return (u32)f2b(lo) | ((u32)f2b(hi) << 16);
}
__device__ __forceinline__ void fma8(const float* x, u32 ux, u32 uy, u32 uz, u32 uw, float& a){
    a += x[0]*lof(ux) + x[1]*hif(ux) + x[2]*lof(uy) + x[3]*hif(uy)
       + x[4]*lof(uz) + x[5]*hif(uz) + x[6]*lof(uw) + x[7]*hif(uw);
}

// Inline per-block dtype sniff (proven rounds 7-11): f32 read as bf16 -> max>100.
__device__ __forceinline__ u32 sniffp(const void* p){
    const u16* s = (const u16*)p;
    float m = 0.f;
    #pragma unroll
    for (int k=0; k<64; k++) m = fmaxf(m, fabsf(bf2f(s[2*k])));
    return (m > 100.f) ? 1u : 0u;
}

// ============ K1: QKV projection + per-head norm + centroid bins ============
// grid (256, 3): 8 tokens/block, y: 0=Q 1=K 2=V. block 512 (8 waves), k-split:
// threads 0-255 accumulate k in [0,256), threads 256-511 k in [256,512);
// W staged per 16-k slice in [512][17] LDS; partial sums reduced through LDS.
__global__ __launch_bounds__(512) void projqkv_kernel(
    const void* __restrict__ Xq, const void* __restrict__ Xk, const void* __restrict__ Xv,
    const void* __restrict__ Wq, const void* __restrict__ bq,
    const void* __restrict__ Wk, const void* __restrict__ bk,
    const void* __restrict__ Wv, const void* __restrict__ bv,
    const void* __restrict__ cen,
    void* __restrict__ outQ,                 // d_out: normalized Q staging (input dtype)
    u16* __restrict__ Kb, u16* __restrict__ Vb,
    u16* __restrict__ qbin, u16* __restrict__ kbin)
{
    int which = blockIdx.y;
    const void *X, *W, *Bb;
    if (which==0){ X=Xq; W=Wq; Bb=bq; }
    else if (which==1){ X=Xk; W=Wk; Bb=bk; }
    else { X=Xv; W=Wv; Bb=bv; }
    u32 fx = sniffp(X), fw = sniffp(W), fb = sniffp(Bb);
    int r0 = blockIdx.x * 8;
    int t = threadIdx.x;           // 0..511
    int ht = t & 255;              // column-pair id (cols ht, ht+256)
    int hb = t >> 8;               // 0 = k-low half, 1 = k-high half

    // wsl phases: W slices [512][17] | reduction [256][17] | centT [64][68] | bvl/bil/nrm2/invn
    __shared__ __align__(16) float wsl[512*17];   // 34816 B
    __shared__ __align__(16) float ps[64*65];     // 16640 B; aliases xstage [8][516]
    float* xstage = ps;

    // stage X tile (8 x 512), coalesced
    for (int i=t; i<1024; i+=512){
        int row = i>>7, c4 = i&127;
        float4 v;
        if (!fx){
            const u32* xp = (const u32*)((const u16*)X + (size_t)(r0+row)*EMBED);
            u32 a = xp[c4*2], b = xp[c4*2+1];
            v = make_float4(lof(a), hif(a), lof(b), hif(b));
        } else {
            v = ((const float4*)((const float*)X + (size_t)(r0+row)*EMBED))[c4];
        }
        *(float4*)(xstage + row*516 + c4*4) = v;
    }

    float acc2[8][2];
    #pragma unroll
    for (int r=0;r<8;r++){ acc2[r][0]=0.f; acc2[r][1]=0.f; }

    // thread t stages W row o=t: 8 floats at k=s*8 and 8 at k=256+s*8
    float4 pf[4];
    {
        int o = t;
        if (!fw){
            const u32* lo = (const u32*)((const u16*)W + (size_t)o*EMBED);
            const u32* hi = (const u32*)((const u16*)W + (size_t)o*EMBED + 256);
            pf[0] = make_float4(lof(lo[0]),hif(lo[0]),lof(lo[1]),hif(lo[1]));
            pf[1] = make_float4(lof(lo[2]),hif(lo[2]),lof(lo[3]),hif(lo[3]));
            pf[2] = make_float4(lof(hi[0]),hif(hi[0]),lof(hi[1]),hif(hi[1]));
            pf[3] = make_float4(lof(hi[2]),hif(hi[2]),lof(hi[3]),hif(hi[3]));
        } else {
            const float4* lo = (const float4*)((const float*)W + (size_t)o*EMBED);
            const float4* hi = (const float4*)((const float*)W + (size_t)o*EMBED + 256);
            pf[0]=lo[0]; pf[1]=lo[1]; pf[2]=hi[0]; pf[3]=hi[1];
        }
    }
    for (int s=0; s<32; s++){
        __syncthreads();                  // xstage ready (s=0) / prev slice consumed
        {
            float* wr = wsl + t*17;
            wr[0]=pf[0].x; wr[1]=pf[0].y; wr[2]=pf[0].z; wr[3]=pf[0].w;
            wr[4]=pf[1].x; wr[5]=pf[1].y; wr[6]=pf[1].z; wr[7]=pf[1].w;
            wr[8]=pf[2].x; wr[9]=pf[2].y; wr[10]=pf[2].z; wr[11]=pf[2].w;
            wr[12]=pf[3].x; wr[13]=pf[3].y; wr[14]=pf[3].z; wr[15]=pf[3].w;
        }
        if (s+1 < 32){
            int o = t, klo = (s+1)*8, khi = 256 + (s+1)*8;
            if (!fw){
                const u32* lo = (const u32*)((const u16*)W + (size_t)o*EMBED + klo);
                const u32* hi = (const u32*)((const u16*)W + (size_t)o*EMBED + khi);
                pf[0] = make_float4(lof(lo[0]),hif(lo[0]),lof(lo[1]),hif(lo[1]));
                pf[1] = make_float4(lof(lo[2]),hif(lo[2]),lof(lo[3]),hif(lo[3]));
                pf[2] = make_float4(lof(hi[0]),hif(hi[0]),lof(hi[1]),hif(hi[1]));
                pf[3] = make_float4(lof(hi[2]),hif(hi[2]),lof(hi[3]),hif(hi[3]));
            } else {
                const float4* lo = (const float4*)((const float*)W + (size_t)o*EMBED + klo);
                const float4* hi = (const float4*)((const float*)W + (size_t)o*EMBED + khi);
                pf[0]=lo[0]; pf[1]=lo[1]; pf[2]=hi[0]; pf[3]=hi[1];
            }
        }
        __syncthreads();
        int coff = hb*8, kg = hb*256 + s*8;
        float w0[8], w1[8];
        #pragma unroll
        for (int kk=0;kk<8;kk++){
            w0[kk] = wsl[ht*17 + coff + kk];
            w1[kk] = wsl[(ht+256)*17 + coff + kk];
        }
        #pragma unroll
        for (int r=0;r<8;r++){
            const float* x = xstage + r*516 + kg;
            float4 x0 = *(const float4*)(x);
            float4 x1 = *(const float4*)(x+4);
            acc2[r][0] += x0.x*w0[0]+x0.y*w0[1]+x0.z*w0[2]+x0.w*w0[3]
                        + x1.x*w0[4]+x1.y*w0[5]+x1.z*w0[6]+x1.w*w0[7];
            acc2[r][1] += x0.x*w1[0]+x0.y*w1[1]+x0.z*w1[2]+x0.w*w1[3]
                        + x1.x*w1[4]+x1.y*w1[5]+x1.z*w1[6]+x1.w*w1[7];
        }
    }
    // reduce halves: B writes partials, A adds + bias + ps
    __syncthreads();
    if (hb == 1){
        float* red = wsl + ht*17;
        #pragma unroll
        for (int r=0;r<8;r++){ red[r*2]=acc2[r][0]; red[r*2+1]=acc2[r][1]; }
    }
    __syncthreads();
    if (hb == 0){
        const float* red = wsl + ht*17;
        float b0 = fb ? ((const float*)Bb)[ht]     : bf2f(((const u16*)Bb)[ht]);
        float b1 = fb ? ((const float*)Bb)[ht+256] : bf2f(((const u16*)Bb)[ht+256]);
        int h0 = ht>>6, c0 = ht&63, h1 = (ht+256)>>6, c1 = (ht+256)&63;
        #pragma unroll
        for (int r=0;r<8;r++){
            ps[(r*8+h0)*65 + c0] = acc2[r][0]+red[r*2]+b0;
            ps[(r*8+h1)*65 + c1] = acc2[r][1]+red[r*2+1]+b1;
        }
    }
    __syncthreads();

    if (which == 2){
        // V: raw bf16 store, 8 elems/thread
        int hr = t>>3, seg = t&7;
        int row = hr>>3, head = hr&7;
        const float* src = ps + hr*65 + seg*8;
        uint4 v;
        v.x = pack2(src[0],src[1]); v.y = pack2(src[2],src[3]);
        v.z = pack2(src[4],src[5]); v.w = pack2(src[6],src[7]);
        *(uint4*)(Vb + (size_t)(r0+row)*EMBED + head*64 + seg*8) = v;
        return;
    }

    // ---------- centroid scan: 1 row x 8 cents per thread, tile prefetch ----------
    u32 fc = sniffp(cen);
    int rg = t>>3, cg = t&7;
    float best = -3.4e38f; int bidx = 0;
    float cpre[8];
    #pragma unroll
    for (int it=0; it<8; it++){
        int e = t + it*512, j = e>>6, k = e&63;
        cpre[it] = fc ? ((const float*)cen)[(size_t)j*HD + k]
                      : bf2f(((const u16*)cen)[(size_t)j*HD + k]);
    }
    for (int tt=0; tt<8; tt++){
        __syncthreads();                 // prev tile consumed / wsl free post-reduce
        #pragma unroll
        for (int it=0; it<8; it++){
            int e = t + it*512, j = e>>6, k = e&63;
            wsl[k*68 + j] = cpre[it];
        }
        if (tt < 7){
            #pragma unroll
            for (int it=0; it<8; it++){
                int e = t + it*512, j = e>>6, k = e&63;
                int gj = (tt+1)*64 + j;
                cpre[it] = fc ? ((const float*)cen)[(size_t)gj*HD + k]
                              : bf2f(((const u16*)cen)[(size_t)gj*HD + k]);
            }
        }
        __syncthreads();
        float acc[8];
        #pragma unroll
        for (int c=0;c<8;c++) acc[c]=0.f;
        const float* pr = ps + rg*65;
        for (int k=0;k<64;k++){
            float a0 = pr[k];
            const float4* cp = (const float4*)(wsl + k*68 + cg*8);
            float4 c0 = cp[0], c1 = cp[1];
            acc[0]+=a0*c0.x; acc[1]+=a0*c0.y; acc[2]+=a0*c0.z; acc[3]+=a0*c0.w;
            acc[4]+=a0*c1.x; acc[5]+=a0*c1.y; acc[6]+=a0*c1.z; acc[7]+=a0*c1.w;
        }
        #pragma unroll
        for (int c=0;c<8;c++){
            int gi = tt*64 + cg*8 + c;   // ascending in-thread -> strict > keeps first max
            if (acc[c] > best){ best=acc[c]; bidx=gi; }
        }
    }
    __syncthreads();                     // last tile reads done; wsl reused for argmax/norm
    float* bvlf = wsl;                   // [64][8]
    int*   bilf = (int*)(wsl + 512);     // [64][8]
    float* nrmf = wsl + 1024;            // [64][8]
    float* invf = wsl + 1536;            // [64]
    bvlf[rg*8+cg] = best; bilf[rg*8+cg] = bidx;
    {
        const float* src = ps + rg*65 + cg*8;
        float ss=0.f;
        #pragma unroll
        for (int d=0;d<8;d++) ss += src[d]*src[d];
        nrmf[rg*8+cg]=ss;
    }
    __syncthreads();
    if (t < 64){
        int hr = t;
        float s2 = 0.f;
        #pragma unroll
        for (int p=0;p<8;p++) s2 += nrmf[hr*8+p];
        invf[hr] = 1.f / fmaxf(sqrtf(s2), 1e-12f);
        float bv = bvlf[hr*8]; int bi = bilf[hr*8];
        #pragma unroll
        for (int g=1; g<8; g++){         // disjoint index sets: (>, ==&&<) merge = np.argmax
            float ov = bvlf[hr*8+g]; int oi = bilf[hr*8+g];
            if (ov > bv || (ov == bv && oi < bi)){ bv = ov; bi = oi; }
        }
        u16* bins = (which==0) ? qbin : kbin;
        int token = r0 + (hr>>3), head = hr&7;
        bins[head*NTOK + token] = (u16)bi;
    }
    __syncthreads();
    {
        int hr = t>>3, seg = t&7;
        float inv = invf[hr];
        const float* src = ps + hr*65 + seg*8;
        int row = hr>>3, head = hr&7;
        size_t off = (size_t)(r0+row)*EMBED + head*64 + seg*8;
        if (which == 1){
            uint4 v;
            v.x = pack2(src[0]*inv, src[1]*inv); v.y = pack2(src[2]*inv, src[3]*inv);
            v.z = pack2(src[4]*inv, src[5]*inv); v.w = pack2(src[6]*inv, src[7]*inv);
            *(uint4*)(Kb + off) = v;
        } else if (!fx){
            uint4 v;
            v.x = pack2(src[0]*inv, src[1]*inv); v.y = pack2(src[2]*inv, src[3]*inv);
            v.z = pack2(src[4]*inv, src[5]*inv); v.w = pack2(src[6]*inv, src[7]*inv);
            *(uint4*)((u16*)outQ + off) = v;
        } else {
            float* dst = (float*)outQ + off;
            ((float4*)dst)[0] = make_float4(src[0]*inv,src[1]*inv,src[2]*inv,src[3]*inv);
            ((float4*)dst)[1] = make_float4(src[4]*inv,src[5]*inv,src[6]*inv,src[7]*inv);
        }
    }
}

// ============ K2: attention — barrier-free, one wave per head ============
// grid 2048 (block per query token), block 512 = 8 waves = 8 heads.
// All LDS regions are per-wave; DS ops are in-order within a wave -> no __syncthreads.
__global__ __launch_bounds__(512) void attn_kernel(
    const void* __restrict__ query,
    const u16* __restrict__ Kb, const u16* __restrict__ Vb,
    const u16* __restrict__ qbin, const u16* __restrict__ kbin,
    void* __restrict__ out)
{
    u32 fq = sniffp(query);
    int q = blockIdx.x;
    int h = threadIdx.x >> 6;
    int lane = threadIdx.x & 63;
    __shared__ float qsh[8][64];
    __shared__ float sc[8][256];
    __shared__ u16   sel[8][256];

    // own-wave q segment -> LDS
    {
        float qv;
        if (!fq) qv = bf2f(((const u16*)out)[(size_t)q*EMBED + h*64 + lane]);
        else     qv = ((const float*)out)[(size_t)q*EMBED + h*64 + lane];
        qsh[h][lane] = qv;
    }
    int myqb = qbin[h*NTOK + q];
    const uint4* kbp = (const uint4*)(kbin + h*NTOK + lane*32);
    u32 fl = 0;
    #pragma unroll
    for (int w4=0; w4<4; w4++){
        uint4 kw = kbp[w4];
        u32 arr[4] = {kw.x, kw.y, kw.z, kw.w};
        #pragma unroll
        for (int e=0;e<4;e++){
            int b0 = (int)(arr[e] & 0xffff), b1 = (int)(arr[e] >> 16);
            int d0 = (myqb - b0) & (NBINS-1), d1 = (myqb - b1) & (NBINS-1);
            if (d0 <= 1 || d0 >= NBINS-1) fl |= 1u << (w4*8 + e*2);
            if (d1 <= 1 || d1 >= NBINS-1) fl |= 1u << (w4*8 + e*2 + 1);
        }
    }
    int cnt = __popc(fl);
    int sum = cnt;
    #pragma unroll
    for (int off=1; off<64; off<<=1){
        int v = __shfl_up(sum, off, 64);
        if (lane >= off) sum += v;
    }
    int total = __shfl(sum, 63, 64);
    int r = sum - cnt;                   // exclusive prefix
    if (total){
        u32 f2 = fl;
        while (f2){
            int j = __ffs(f2) - 1; f2 &= f2 - 1;   // ascending -> index order
            if (r < MAXSEL) sel[h][r] = (u16)(lane*32 + j);
            r++;
        }
    } else {
        #pragma unroll
        for (int kq=0;kq<4;kq++) sel[h][lane*4+kq] = (u16)(lane*4+kq);
    }
    int L = total ? min(total, MAXSEL) : MAXSEL;

    const float* qh = qsh[h];
    float mloc = -3.4e38f;
    for (int jj=lane; jj<L; jj+=64){
        int kkey = sel[h][jj];
        const uint4* kr = (const uint4*)(Kb + (size_t)kkey*EMBED + h*64);
        float acc = 0.f;
        #pragma unroll
        for (int p=0;p<8;p++){ uint4 u = kr[p]; fma8(qh+p*8, u.x,u.y,u.z,u.w, acc); }
        float s = acc * 0.125f;
        sc[h][jj] = s;
        mloc = fmaxf(mloc, s);
    }
    #pragma unroll
    for (int off=32; off; off>>=1) mloc = fmaxf(mloc, __shfl_xor(mloc, off, 64));
    float ssum = 0.f;
    for (int jj=lane; jj<L; jj+=64){
        float e = __expf(sc[h][jj] - mloc);
        sc[h][jj] = e; ssum += e;
    }
    #pragma unroll
    for (int off=32; off; off>>=1) ssum += __shfl_xor(ssum, off, 64);
    float inv = 1.f / fmaxf(ssum, 1e-37f);
    float acc = 0.f;
    for (int j=0; j<L; j++){
        int kkey = sel[h][j];
        acc += sc[h][j] * bf2f(Vb[(size_t)kkey*EMBED + h*64 + lane]);
    }
    float o = acc * inv;
    if (!fq) ((u16*)out)[(size_t)q*EMBED + h*64 + lane] = f2b(o);
    else     ((float*)out)[(size_t)q*EMBED + h*64 + lane] = o;
}

// ============ K3: output projection, in place on d_out ============
// grid 512: 4 rows/block, block 512, k-split like K1.
__global__ __launch_bounds__(512) void oproj_kernel(
    void* __restrict__ out, const void* __restrict__ Wo, const void* __restrict__ bo)
{
    u32 fq = sniffp(out);
    u32 fw = sniffp(Wo), fb = sniffp(bo);
    int r0 = blockIdx.x * 4;
    int t = threadIdx.x;
    int ht = t & 255, hb = t >> 8;
    __shared__ __align__(16) float wsl[512*17];   // 34816 B
    __shared__ __align__(16) float xst[4*516];    // 8256 B

    for (int i=t; i<512; i+=512){
        int row = i>>7, c4 = i&127;
        float4 v;
        if (!fq){
            const u32* xp = (const u32*)((const u16*)out + (size_t)(r0+row)*EMBED);
            u32 a = xp[c4*2], b = xp[c4*2+1];
            v = make_float4(lof(a), hif(a), lof(b), hif(b));
        } else {
            v = ((const float4*)((const float*)out + (size_t)(r0+row)*EMBED))[c4];
        }
        *(float4*)(xst + row*516 + c4*4) = v;
    }

    float acc2[4][2];
    #pragma unroll
    for (int r=0;r<4;r++){ acc2[r][0]=0.f; acc2[r][1]=0.f; }

    float4 pf[4];
    {
        int o = t;
        if (!fw){
            const u32* lo = (const u32*)((const u16*)Wo + (size_t)o*EMBED);
            const u32* hi = (const u32*)((const u16*)Wo + (size_t)o*EMBED + 256);
            pf[0] = make_float4(lof(lo[0]),hif(lo[0]),lof(lo[1]),hif(lo[1]));
            pf[1] = make_float4(lof(lo[2]),hif(lo[2]),lof(lo[3]),hif(lo[3]));
            pf[2] = make_float4(lof(hi[0]),hif(hi[0]),lof(hi[1]),hif(hi[1]));
            pf[3] = make_float4(lof(hi[2]),hif(hi[2]),lof(hi[3]),hif(hi[3]));
        } else {
            const float4* lo = (const float4*)((const float*)Wo + (size_t)o*EMBED);
            const float4* hi = (const float4*)((const float*)Wo + (size_t)o*EMBED + 256);
            pf[0]=lo[0]; pf[1]=lo[1]; pf[2]=hi[0]; pf[3]=hi[1];
        }
    }
    for (int s=0; s<32; s++){
        __syncthreads();
        {
            float* wr = wsl + t*17;
            wr[0]=pf[0].x; wr[1]=pf[0].y; wr[2]=pf[0].z; wr[3]=pf[0].w;
            wr[4]=pf[1].x; wr[5]=pf[1].y; wr[6]=pf[1].z; wr[7]=pf[1].w;
            wr[8]=pf[2].x; wr[9]=pf[2].y; wr[10]=pf[2].z; wr[11]=pf[2].w;
            wr[12]=pf[3].x; wr[13]=pf[3].y; wr[14]=pf[3].z; wr[15]=pf[3].w;
        }
        if (s+1 < 32){
            int o = t, klo = (s+1)*8, khi = 256 + (s+1)*8;
            if (!fw){
                const u32* lo = (const u32*)((const u16*)Wo + (size_t)o*EMBED + klo);
                const u32* hi = (const u32*)((const u16*)Wo + (size_t)o*EMBED + khi);
                pf[0] = make_float4(lof(lo[0]),hif(lo[0]),lof(lo[1]),hif(lo[1]));
                pf[1] = make_float4(lof(lo[2]),hif(lo[2]),lof(lo[3]),hif(lo[3]));
                pf[2] = make_float4(lof(hi[0]),hif(hi[0]),lof(hi[1]),hif(hi[1]));
                pf[3] = make_float4(lof(hi[2]),hif(hi[2]),lof(hi[3]),hif(hi[3]));
            } else {
                const float4* lo = (const float4*)((const float*)Wo + (size_t)o*EMBED + klo);
                const float4* hi = (const float4*)((const float*)Wo + (size_t)o*EMBED + khi);
                pf[0]=lo[0]; pf[1]=lo[1]; pf[2]=hi[0]; pf[3]=hi[1];
            }
        }
        __syncthreads();
        int coff = hb*8, kg = hb*256 + s*8;
        float w0[8], w1[8];
        #pragma unroll
        for (int kk=0;kk<8;kk++){
            w0[kk] = wsl[ht*17 + coff + kk];
            w1[kk] = wsl[(ht+256)*17 + coff + kk];
        }
        #pragma unroll
        for (int r=0;r<4;r++){
            const float* x = xst + r*516 + kg;
            float4 x0 = *(const float4*)(x);
            float4 x1 = *(const float4*)(x+4);
            acc2[r][0] += x0.x*w0[0]+x0.y*w0[1]+x0.z*w0[2]+x0.w*w0[3]
                        + x1.x*w0[4]+x1.y*w0[5]+x1.z*w0[6]+x1.w*w0[7];
            acc2[r][1] += x0.x*w1[0]+x0.y*w1[1]+x0.z*w1[2]+x0.w*w1[3]
                        + x1.x*w1[4]+x1.y*w1[5]+x1.z*w1[6]+x1.w*w1[7];
        }
    }
    __syncthreads();
    if (hb == 1){
        float* red = wsl + ht*9;
        #pragma unroll
        for (int r=0;r<4;r++){ red[r*2]=acc2[r][0]; red[r*2+1]=acc2[r][1]; }
    }
    __syncthreads();
    if (hb == 0){
        const float* red = wsl + ht*9;
        float b0 = fb ? ((const float*)bo)[ht]     : bf2f(((const u16*)bo)[ht]);
        float b1 = fb ? ((const float*)bo)[ht+256] : bf2f(((const u16*)bo)[ht+256]);
        if (!fq){
            u16* o = (u16*)out;
            #pragma unroll
            for (int r=0;r<4;r++){
                o[(size_t)(r0+r)*EMBED + ht]       = f2b(acc2[r][0]+red[r*2]+b0);
                o[(size_t)(r0+r)*EMBED + ht + 256] = f2b(acc2[r][1]+red[r*2+1]+b1);
            }
        } else {
            float* o = (float*)out;
            #pragma unroll
            for (int r=0;r<4;r++){
                o[(size_t)(r0+r)*EMBED + ht]       = acc2[r][0]+red[r*2]+b0;
                o[(size_t)(r0+r)*EMBED + ht + 256] = acc2[r][1]+red[r*2+1]+b1;
            }
        }
    }
}

extern "C" void kernel_launch(void* const* d_in, const int* in_sizes, int n_in,
                              void* d_out, int out_size, void* d_ws, size_t ws_size,
                              hipStream_t stream)
{
    const void* query = d_in[0];
    const void* key   = d_in[1];
    const void* value = d_in[2];
    const void* Wq = d_in[3];
    const void* bq = d_in[4];
    const void* Wk = d_in[5];
    const void* bk = d_in[6];
    const void* Wv = d_in[7];
    const void* bv = d_in[8];
    const void* Wo = d_in[9];
    const void* bo = d_in[10];
    const void* cen = d_in[11];

    // ws layout (4,259,840 B — proven footprint since round 7):
    //   [0, 32K)        qbin u16[16384]
    //   [32K, 64K)      kbin u16[16384]
    //   [64K, 64K+2M)   Kb bf16 (normalized)
    //   [64K+2M, +2M)   Vb bf16 (raw)
    char* ws = (char*)d_ws;
    u16* qbin = (u16*)ws;
    u16* kbin = (u16*)(ws + 32768);
    u16* Kb   = (u16*)(ws + 65536);
    u16* Vb   = (u16*)(ws + 65536 + (size_t)2*1024*1024);

    projqkv_kernel<<<dim3(256,3), 512, 0, stream>>>(query,key,value,Wq,bq,Wk,bk,Wv,bv,cen,
                                                    d_out,Kb,Vb,qbin,kbin);
    attn_kernel<<<2048, 512, 0, stream>>>(query,Kb,Vb,qbin,kbin,d_out);
    oproj_kernel<<<512, 512, 0, stream>>>(d_out,Wo,bo);
}

// Round 13
// 343.066 us; speedup vs baseline: 1.0851x; 1.0851x over previous
//
#include <hip/hip_runtime.h>
#include <hip/hip_bf16.h>

#define NTOK 2048
#define EMBED 512
#define NHEADS 8
#define HD 64
#define NBINS 512
#define MAXSEL 256

typedef unsigned short u16;
typedef unsigned int u32;
typedef short s16x8 __attribute__((ext_vector_type(8)));
typedef float f32x4 __attribute__((ext_vector_type(4)));

__device__ __forceinline__ float lof(u32 u){ return __uint_as_float(u << 16); }
__device__ __forceinline__ float hif(u32 u){ return __uint_as_float(u & 0xffff0000u); }
__device__ __forceinline__ float bf2f(u16 u){ return __uint_as_float(((u32)u) << 16); }
__device__ __forceinline__ u16 f2b(float f){
    __hip_bfloat16 h = __float2bfloat16(f);
    return *(u16*)&h;
}
__device__ __forceinline__ u32 pack2(float lo, float hi){
    return (u32)f2b(lo) | ((u32)f2b(hi) << 16);
}
__device__ __forceinline__ void fma8(const float* x, u32 ux, u32 uy, u32 uz, u32 uw, float& a){
    a += x[0]*lof(ux) + x[1]*hif(ux) + x[2]*lof(uy) + x[3]*hif(uy)
       + x[4]*lof(uz) + x[5]*hif(uz) + x[6]*lof(uw) + x[7]*hif(uw);
}

// Inline per-block dtype sniff (proven rounds 7-12): f32 read as bf16 -> max>100.
__device__ __forceinline__ u32 sniffp(const void* p){
    const u16* s = (const u16*)p;
    float m = 0.f;
    #pragma unroll
    for (int k=0; k<64; k++) m = fmaxf(m, fabsf(bf2f(s[2*k])));
    return (m > 100.f) ? 1u : 0u;
}

// ============ K1: Q/K projection + per-head norm + centroid bins ============
// Round-11-proven structure. grid (256, 2): 8 tokens/block, y: 0=Q 1=K. block 256.
// f32 GEMM (bins must be f32-faithful); W k-slices through LDS with register prefetch.
__global__ __launch_bounds__(256) void projqk_kernel(
    const void* __restrict__ Xq, const void* __restrict__ Xk,
    const void* __restrict__ Wq, const void* __restrict__ bq,
    const void* __restrict__ Wk, const void* __restrict__ bk,
    const void* __restrict__ cen,
    void* __restrict__ outQ,                 // d_out: normalized Q staging (input dtype)
    u16* __restrict__ Kb,
    u16* __restrict__ qbin, u16* __restrict__ kbin)
{
    int which = blockIdx.y;                  // 0=Q, 1=K
    const void *X = which ? Xk : Xq;
    const void *W = which ? Wk : Wq;
    const void *Bb = which ? bk : bq;
    u32 fx = sniffp(X), fw = sniffp(W), fb = sniffp(Bb);
    int r0 = blockIdx.x * 8;
    int t = threadIdx.x;

    __shared__ __align__(16) float ubuf[4608];  // wslice [512][9] / scan centT [64][68]
    __shared__ __align__(16) float ps[64*65];   // results [(tok*8+head)][65]; aliases xstage
    __shared__ float nrm2[64][4];
    __shared__ float invn[64];
    __shared__ float bvl[64][8];
    __shared__ int   bil[64][8];

    float* xstage = ps;
    for (int i=t; i<1024; i+=256){
        int row = i>>7, c4 = i&127;
        float4 v;
        if (!fx){
            const u32* xp = (const u32*)((const u16*)X + (size_t)(r0+row)*EMBED);
            u32 a = xp[c4*2], b = xp[c4*2+1];
            v = make_float4(lof(a), hif(a), lof(b), hif(b));
        } else {
            v = ((const float4*)((const float*)X + (size_t)(r0+row)*EMBED))[c4];
        }
        *(float4*)(xstage + row*516 + c4*4) = v;
    }

    float acc2[8][2];
    #pragma unroll
    for (int r=0;r<8;r++){ acc2[r][0]=0.f; acc2[r][1]=0.f; }

    float4 pf[4];
    #pragma unroll
    for (int it=0; it<4; it++){
        int j = t + it*256, o = j>>1, half = j&1;
        if (!fw){
            const u32* wp2 = (const u32*)((const u16*)W + (size_t)o*EMBED + half*4);
            pf[it] = make_float4(lof(wp2[0]), hif(wp2[0]), lof(wp2[1]), hif(wp2[1]));
        } else {
            pf[it] = *(const float4*)((const float*)W + (size_t)o*EMBED + half*4);
        }
    }
    for (int k0=0; k0<512; k0+=8){
        __syncthreads();
        #pragma unroll
        for (int it=0; it<4; it++){
            int j = t + it*256, o = j>>1, kb = (j&1)*4;
            ubuf[o*9+kb+0]=pf[it].x; ubuf[o*9+kb+1]=pf[it].y;
            ubuf[o*9+kb+2]=pf[it].z; ubuf[o*9+kb+3]=pf[it].w;
        }
        if (k0+8 < 512){
            int kn = k0+8;
            #pragma unroll
            for (int it=0; it<4; it++){
                int j = t + it*256, o = j>>1, half = j&1;
                if (!fw){
                    const u32* wp2 = (const u32*)((const u16*)W + (size_t)o*EMBED + kn + half*4);
                    pf[it] = make_float4(lof(wp2[0]), hif(wp2[0]), lof(wp2[1]), hif(wp2[1]));
                } else {
                    pf[it] = *(const float4*)((const float*)W + (size_t)o*EMBED + kn + half*4);
                }
            }
        }
        __syncthreads();
        float w0[8], w1[8];
        #pragma unroll
        for (int kk=0;kk<8;kk++){
            w0[kk] = ubuf[t*9+kk];
            w1[kk] = ubuf[(t+256)*9+kk];
        }
        #pragma unroll
        for (int r=0;r<8;r++){
            const float* x = xstage + r*516 + k0;
            float4 x0 = *(const float4*)(x);
            float4 x1 = *(const float4*)(x+4);
            acc2[r][0] += x0.x*w0[0]+x0.y*w0[1]+x0.z*w0[2]+x0.w*w0[3]
                        + x1.x*w0[4]+x1.y*w0[5]+x1.z*w0[6]+x1.w*w0[7];
            acc2[r][1] += x0.x*w1[0]+x0.y*w1[1]+x0.z*w1[2]+x0.w*w1[3]
                        + x1.x*w1[4]+x1.y*w1[5]+x1.z*w1[6]+x1.w*w1[7];
        }
    }
    __syncthreads();
    {
        float b0 = fb ? ((const float*)Bb)[t]     : bf2f(((const u16*)Bb)[t]);
        float b1 = fb ? ((const float*)Bb)[t+256] : bf2f(((const u16*)Bb)[t+256]);
        int h0 = t>>6, c0 = t&63, h1 = (t+256)>>6, c1 = (t+256)&63;
        #pragma unroll
        for (int r=0;r<8;r++){
            ps[(r*8+h0)*65 + c0] = acc2[r][0]+b0;
            ps[(r*8+h1)*65 + c1] = acc2[r][1]+b1;
        }
    }
    __syncthreads();

    // ---------- centroid scan (f32-faithful) ----------
    u32 fc = sniffp(cen);
    int rg = t>>3, cg = t&7;
    float best[2] = {-3.4e38f,-3.4e38f};
    int   bidx[2] = {0,0};
    float cpre[16];
    #pragma unroll
    for (int it=0; it<16; it++){
        int e = t + it*256, j = e>>6, k = e&63;
        cpre[it] = fc ? ((const float*)cen)[(size_t)j*HD + k]
                      : bf2f(((const u16*)cen)[(size_t)j*HD + k]);
    }
    for (int tt=0; tt<8; tt++){
        __syncthreads();
        #pragma unroll
        for (int it=0; it<16; it++){
            int e = t + it*256, j = e>>6, k = e&63;
            ubuf[k*68 + j] = cpre[it];
        }
        if (tt < 7){
            #pragma unroll
            for (int it=0; it<16; it++){
                int e = t + it*256, j = e>>6, k = e&63;
                int gj = (tt+1)*64 + j;
                cpre[it] = fc ? ((const float*)cen)[(size_t)gj*HD + k]
                              : bf2f(((const u16*)cen)[(size_t)gj*HD + k]);
            }
        }
        __syncthreads();
        float acc[2][8];
        #pragma unroll
        for (int j=0;j<2;j++)
            #pragma unroll
            for (int c=0;c<8;c++) acc[j][c]=0.f;
        const float* pr0 = ps + (2*rg)*65;
        const float* pr1 = pr0 + 65;
        for (int k=0;k<64;k++){
            float a0 = pr0[k], a1 = pr1[k];
            const float4* cp = (const float4*)(ubuf + k*68 + cg*8);
            float4 c0 = cp[0], c1 = cp[1];
            acc[0][0]+=a0*c0.x; acc[0][1]+=a0*c0.y; acc[0][2]+=a0*c0.z; acc[0][3]+=a0*c0.w;
            acc[0][4]+=a0*c1.x; acc[0][5]+=a0*c1.y; acc[0][6]+=a0*c1.z; acc[0][7]+=a0*c1.w;
            acc[1][0]+=a1*c0.x; acc[1][1]+=a1*c0.y; acc[1][2]+=a1*c0.z; acc[1][3]+=a1*c0.w;
            acc[1][4]+=a1*c1.x; acc[1][5]+=a1*c1.y; acc[1][6]+=a1*c1.z; acc[1][7]+=a1*c1.w;
        }
        #pragma unroll
        for (int j=0;j<2;j++){
            #pragma unroll
            for (int c=0;c<8;c++){
                int gi = tt*64 + cg*8 + c;   // ascending in-thread -> strict > keeps first
                if (acc[j][c] > best[j]){ best[j]=acc[j][c]; bidx[j]=gi; }
            }
        }
    }
    bvl[2*rg  ][cg]=best[0]; bil[2*rg  ][cg]=bidx[0];
    bvl[2*rg+1][cg]=best[1]; bil[2*rg+1][cg]=bidx[1];
    {
        int hr = t>>2, q4 = t&3;
        const float* src = ps + hr*65 + q4*16;
        float ss=0.f;
        #pragma unroll
        for (int d=0;d<16;d++) ss += src[d]*src[d];
        nrm2[hr][q4]=ss;
    }
    __syncthreads();
    if (t < 64){
        int hr = t;
        invn[hr] = 1.f / fmaxf(sqrtf(nrm2[hr][0]+nrm2[hr][1]+nrm2[hr][2]+nrm2[hr][3]), 1e-12f);
        float bv = bvl[hr][0]; int bi = bil[hr][0];
        #pragma unroll
        for (int g=1; g<8; g++){         // disjoint index sets: (>, ==&&<) merge = np.argmax
            float ov = bvl[hr][g]; int oi = bil[hr][g];
            if (ov > bv || (ov == bv && oi < bi)){ bv = ov; bi = oi; }
        }
        u16* bins = (which==0) ? qbin : kbin;
        int token = r0 + (hr>>3), head = hr&7;
        bins[head*NTOK + token] = (u16)bi;
    }
    __syncthreads();
    {
        int hr = t>>2, q4 = t&3;
        float inv = invn[hr];
        const float* src = ps + hr*65 + q4*16;
        int row = hr>>3, head = hr&7;
        size_t off = (size_t)(r0+row)*EMBED + head*64 + q4*16;
        if (which == 1){
            u16* dst = Kb + off;
            #pragma unroll
            for (int j8=0;j8<2;j8++){
                uint4 v;
                v.x = pack2(src[j8*8+0]*inv, src[j8*8+1]*inv);
                v.y = pack2(src[j8*8+2]*inv, src[j8*8+3]*inv);
                v.z = pack2(src[j8*8+4]*inv, src[j8*8+5]*inv);
                v.w = pack2(src[j8*8+6]*inv, src[j8*8+7]*inv);
                ((uint4*)dst)[j8] = v;
            }
        } else if (!fx){
            u16* dst = (u16*)outQ + off;
            #pragma unroll
            for (int j8=0;j8<2;j8++){
                uint4 v;
                v.x = pack2(src[j8*8+0]*inv, src[j8*8+1]*inv);
                v.y = pack2(src[j8*8+2]*inv, src[j8*8+3]*inv);
                v.z = pack2(src[j8*8+4]*inv, src[j8*8+5]*inv);
                v.w = pack2(src[j8*8+6]*inv, src[j8*8+7]*inv);
                ((uint4*)dst)[j8] = v;
            }
        } else {
            float* dst = (float*)outQ + off;
            #pragma unroll
            for (int j4=0;j4<4;j4++){
                float4 v = make_float4(src[j4*4+0]*inv, src[j4*4+1]*inv,
                                       src[j4*4+2]*inv, src[j4*4+3]*inv);
                ((float4*)dst)[j4] = v;
            }
        }
    }
}

// ============ K1b: V projection via MFMA (bf16 — V feeds no argmax) ============
// grid 128: 16 tokens/block, block 256 (4 waves x 128 cols).
// A[m=lane&15][k=quad*8+j] from LDS; B[n=lane&15][k] from W row o (k-contiguous);
// D: col=lane&15, row=quad*4+reg  (guide-verified 16x16x32 layouts).
__global__ __launch_bounds__(256) void projv_kernel(
    const void* __restrict__ Xv, const void* __restrict__ Wv, const void* __restrict__ bv,
    u16* __restrict__ Vb)
{
    u32 fx = sniffp(Xv), fw = sniffp(Wv), fb = sniffp(bv);
    int r0 = blockIdx.x * 16;
    int t = threadIdx.x;
    __shared__ u16 xsb[16*520];

    {   // stage X tile -> bf16 LDS (32 elems = 4 uint4 per thread)
        int row = t>>4, seg = t&15;
        u16* dst = xsb + row*520 + seg*32;
        if (!fx){
            const uint4* src = (const uint4*)((const u16*)Xv + (size_t)(r0+row)*EMBED + seg*32);
            #pragma unroll
            for (int j=0;j<4;j++) ((uint4*)dst)[j] = src[j];
        } else {
            const float4* src = (const float4*)((const float*)Xv + (size_t)(r0+row)*EMBED + seg*32);
            #pragma unroll
            for (int j=0;j<4;j++){
                float4 a = src[j*2], b = src[j*2+1];
                uint4 v;
                v.x = pack2(a.x,a.y); v.y = pack2(a.z,a.w);
                v.z = pack2(b.x,b.y); v.w = pack2(b.z,b.w);
                ((uint4*)dst)[j] = v;
            }
        }
    }
    __syncthreads();
    int lane = t&63, wave = t>>6;
    int m = lane&15, quad = lane>>4;
    int obase = wave*128;
    f32x4 acc[8];
    #pragma unroll
    for (int i=0;i<8;i++){ f32x4 z = {0.f,0.f,0.f,0.f}; acc[i] = z; }
    const u16* arow = xsb + m*520 + quad*8;
    for (int k=0;k<16;k++){
        s16x8 a = *(const s16x8*)(arow + k*32);
        #pragma unroll
        for (int tile=0;tile<8;tile++){
            int o = obase + tile*16 + m;
            s16x8 b;
            if (!fw){
                b = *(const s16x8*)((const u16*)Wv + (size_t)o*EMBED + k*32 + quad*8);
            } else {
                const float4* wp = (const float4*)((const float*)Wv + (size_t)o*EMBED + k*32 + quad*8);
                float4 w0 = wp[0], w1 = wp[1];
                union { u32 u[4]; s16x8 v; } bb;
                bb.u[0] = pack2(w0.x,w0.y); bb.u[1] = pack2(w0.z,w0.w);
                bb.u[2] = pack2(w1.x,w1.y); bb.u[3] = pack2(w1.z,w1.w);
                b = bb.v;
            }
            acc[tile] = __builtin_amdgcn_mfma_f32_16x16x32_bf16(a, b, acc[tile], 0, 0, 0);
        }
    }
    #pragma unroll
    for (int tile=0;tile<8;tile++){
        int o = obase + tile*16 + m;
        float bias = fb ? ((const float*)bv)[o] : bf2f(((const u16*)bv)[o]);
        #pragma unroll
        for (int reg=0;reg<4;reg++){
            int row = quad*4 + reg;
            Vb[(size_t)(r0+row)*EMBED + o] = f2b(acc[tile][reg] + bias);
        }
    }
}

// ============ K2: attention — barrier-free, one wave per head (round-12-proven) ============
__global__ __launch_bounds__(512) void attn_kernel(
    const void* __restrict__ query,
    const u16* __restrict__ Kb, const u16* __restrict__ Vb,
    const u16* __restrict__ qbin, const u16* __restrict__ kbin,
    void* __restrict__ out)
{
    u32 fq = sniffp(query);
    int q = blockIdx.x;
    int h = threadIdx.x >> 6;
    int lane = threadIdx.x & 63;
    __shared__ float qsh[8][64];
    __shared__ float sc[8][256];
    __shared__ u16   sel[8][256];

    {
        float qv;
        if (!fq) qv = bf2f(((const u16*)out)[(size_t)q*EMBED + h*64 + lane]);
        else     qv = ((const float*)out)[(size_t)q*EMBED + h*64 + lane];
        qsh[h][lane] = qv;
    }
    int myqb = qbin[h*NTOK + q];
    const uint4* kbp = (const uint4*)(kbin + h*NTOK + lane*32);
    u32 fl = 0;
    #pragma unroll
    for (int w4=0; w4<4; w4++){
        uint4 kw = kbp[w4];
        u32 arr[4] = {kw.x, kw.y, kw.z, kw.w};
        #pragma unroll
        for (int e=0;e<4;e++){
            int b0 = (int)(arr[e] & 0xffff), b1 = (int)(arr[e] >> 16);
            int d0 = (myqb - b0) & (NBINS-1), d1 = (myqb - b1) & (NBINS-1);
            if (d0 <= 1 || d0 >= NBINS-1) fl |= 1u << (w4*8 + e*2);
            if (d1 <= 1 || d1 >= NBINS-1) fl |= 1u << (w4*8 + e*2 + 1);
        }
    }
    int cnt = __popc(fl);
    int sum = cnt;
    #pragma unroll
    for (int off=1; off<64; off<<=1){
        int v = __shfl_up(sum, off, 64);
        if (lane >= off) sum += v;
    }
    int total = __shfl(sum, 63, 64);
    int r = sum - cnt;
    if (total){
        u32 f2 = fl;
        while (f2){
            int j = __ffs(f2) - 1; f2 &= f2 - 1;
            if (r < MAXSEL) sel[h][r] = (u16)(lane*32 + j);
            r++;
        }
    } else {
        #pragma unroll
        for (int kq=0;kq<4;kq++) sel[h][lane*4+kq] = (u16)(lane*4+kq);
    }
    int L = total ? min(total, MAXSEL) : MAXSEL;

    const float* qh = qsh[h];
    float mloc = -3.4e38f;
    for (int jj=lane; jj<L; jj+=64){
        int kkey = sel[h][jj];
        const uint4* kr = (const uint4*)(Kb + (size_t)kkey*EMBED + h*64);
        float acc = 0.f;
        #pragma unroll
        for (int p=0;p<8;p++){ uint4 u = kr[p]; fma8(qh+p*8, u.x,u.y,u.z,u.w, acc); }
        float s = acc * 0.125f;
        sc[h][jj] = s;
        mloc = fmaxf(mloc, s);
    }
    #pragma unroll
    for (int off=32; off; off>>=1) mloc = fmaxf(mloc, __shfl_xor(mloc, off, 64));
    float ssum = 0.f;
    for (int jj=lane; jj<L; jj+=64){
        float e = __expf(sc[h][jj] - mloc);
        sc[h][jj] = e; ssum += e;
    }
    #pragma unroll
    for (int off=32; off; off>>=1) ssum += __shfl_xor(ssum, off, 64);
    float inv = 1.f / fmaxf(ssum, 1e-37f);
    float acc = 0.f;
    for (int j=0; j<L; j++){
        int kkey = sel[h][j];
        acc += sc[h][j] * bf2f(Vb[(size_t)kkey*EMBED + h*64 + lane]);
    }
    float o = acc * inv;
    if (!fq) ((u16*)out)[(size_t)q*EMBED + h*64 + lane] = f2b(o);
    else     ((float*)out)[(size_t)q*EMBED + h*64 + lane] = o;
}

// ============ K3: output projection via MFMA, in place on d_out ============
// grid 128: 16 rows/block. Stages rows (cast to bf16) BEFORE overwrite.
// Output error from bf16 inputs ~2e-3 << 0.031 threshold; no argmax downstream.
__global__ __launch_bounds__(256) void oproj_kernel(
    void* __restrict__ out, const void* __restrict__ Wo, const void* __restrict__ bo)
{
    u32 fq = sniffp(out);
    u32 fw = sniffp(Wo), fb = sniffp(bo);
    int r0 = blockIdx.x * 16;
    int t = threadIdx.x;
    __shared__ u16 ab[16*520];

    {
        int row = t>>4, seg = t&15;
        u16* dst = ab + row*520 + seg*32;
        if (!fq){
            const uint4* src = (const uint4*)((const u16*)out + (size_t)(r0+row)*EMBED + seg*32);
            #pragma unroll
            for (int j=0;j<4;j++) ((uint4*)dst)[j] = src[j];
        } else {
            const float4* src = (const float4*)((const float*)out + (size_t)(r0+row)*EMBED + seg*32);
            #pragma unroll
            for (int j=0;j<4;j++){
                float4 a = src[j*2], b = src[j*2+1];
                uint4 v;
                v.x = pack2(a.x,a.y); v.y = pack2(a.z,a.w);
                v.z = pack2(b.x,b.y); v.w = pack2(b.z,b.w);
                ((uint4*)dst)[j] = v;
            }
        }
    }
    __syncthreads();
    int lane = t&63, wave = t>>6;
    int m = lane&15, quad = lane>>4;
    int obase = wave*128;
    f32x4 acc[8];
    #pragma unroll
    for (int i=0;i<8;i++){ f32x4 z = {0.f,0.f,0.f,0.f}; acc[i] = z; }
    const u16* arow = ab + m*520 + quad*8;
    for (int k=0;k<16;k++){
        s16x8 a = *(const s16x8*)(arow + k*32);
        #pragma unroll
        for (int tile=0;tile<8;tile++){
            int o = obase + tile*16 + m;
            s16x8 b;
            if (!fw){
                b = *(const s16x8*)((const u16*)Wo + (size_t)o*EMBED + k*32 + quad*8);
            } else {
                const float4* wp = (const float4*)((const float*)Wo + (size_t)o*EMBED + k*32 + quad*8);
                float4 w0 = wp[0], w1 = wp[1];
                union { u32 u[4]; s16x8 v; } bb;
                bb.u[0] = pack2(w0.x,w0.y); bb.u[1] = pack2(w0.z,w0.w);
                bb.u[2] = pack2(w1.x,w1.y); bb.u[3] = pack2(w1.z,w1.w);
                b = bb.v;
            }
            acc[tile] = __builtin_amdgcn_mfma_f32_16x16x32_bf16(a, b, acc[tile], 0, 0, 0);
        }
    }
    #pragma unroll
    for (int tile=0;tile<8;tile++){
        int o = obase + tile*16 + m;
        float bias = fb ? ((const float*)bo)[o] : bf2f(((const u16*)bo)[o]);
        #pragma unroll
        for (int reg=0;reg<4;reg++){
            int row = quad*4 + reg;
            float v = acc[tile][reg] + bias;
            if (!fq) ((u16*)out)[(size_t)(r0+row)*EMBED + o] = f2b(v);
            else     ((float*)out)[(size_t)(r0+row)*EMBED + o] = v;
        }
    }
}

extern "C" void kernel_launch(void* const* d_in, const int* in_sizes, int n_in,
                              void* d_out, int out_size, void* d_ws, size_t ws_size,
                              hipStream_t stream)
{
    const void* query = d_in[0];
    const void* key   = d_in[1];
    const void* value = d_in[2];
    const void* Wq = d_in[3];
    const void* bq = d_in[4];
    const void* Wk = d_in[5];
    const void* bk = d_in[6];
    const void* Wv = d_in[7];
    const void* bv = d_in[8];
    const void* Wo = d_in[9];
    const void* bo = d_in[10];
    const void* cen = d_in[11];

    // ws layout (4,259,840 B — proven footprint since round 7):
    //   [0, 32K)        qbin u16[16384]
    //   [32K, 64K)      kbin u16[16384]
    //   [64K, 64K+2M)   Kb bf16 (normalized)
    //   [64K+2M, +2M)   Vb bf16 (raw)
    char* ws = (char*)d_ws;
    u16* qbin = (u16*)ws;
    u16* kbin = (u16*)(ws + 32768);
    u16* Kb   = (u16*)(ws + 65536);
    u16* Vb   = (u16*)(ws + 65536 + (size_t)2*1024*1024);

    projqk_kernel<<<dim3(256,2), 256, 0, stream>>>(query,key,Wq,bq,Wk,bk,cen,
                                                   d_out,Kb,qbin,kbin);
    projv_kernel<<<128, 256, 0, stream>>>(value,Wv,bv,Vb);
    attn_kernel<<<2048, 512, 0, stream>>>(query,Kb,Vb,qbin,kbin,d_out);
    oproj_kernel<<<128, 256, 0, stream>>>(d_out,Wo,bo);
}